// Round 5
// baseline (545.424 us; speedup 1.0000x reference)
//
#include <hip/hip_runtime.h>

typedef short short8 __attribute__((ext_vector_type(8)));
typedef float f32x4 __attribute__((ext_vector_type(4)));

__device__ __forceinline__ unsigned short f2bf(float f) {
    unsigned int u = __float_as_uint(f);
    u = (u + 0x7fffu + ((u >> 16) & 1u)) >> 16;
    return (unsigned short)u;
}

// ======== workspace byte offsets ========
// h1p  : 0          (64,130,130,32) bf16  69,222,400 B
// h2p  : 69222400   (64,66,66,64)  bf16   35,684,352 B
// zeN  : 104906752  (64,64,64,64)  bf16   33,554,432 B
// zqp  : 138461184  (64,66,66,64)  bf16   35,684,352 B
// d1op : 174145536  (64,66,66,32)  bf16   17,842,176 B
// score: 191987712  (1048576,16)   f32    67,108,864 B
// ape2 : 259096576  65536 B ; ape3: 259162112 73728 B ; apd1: 259235840 36864 B
// apd2 : 259272704  65536 B ; apd3: 259338240 2048 B  ; embbf: 259340288 65536 B
// hninit: 259405824 2048 B   (= 2.0 - 0.5*||e||^2)

// ---------------- merged init: halo zeroing + weight prep ----------------
__global__ __launch_bounds__(256) void k_init(
    unsigned int* __restrict__ ws_dw,
    const float* __restrict__ e2w, const float* __restrict__ e3w,
    const float* __restrict__ d1w, const float* __restrict__ d2w,
    const float* __restrict__ d3w, const float* __restrict__ emb,
    unsigned short* __restrict__ ape2, unsigned short* __restrict__ ape3,
    unsigned short* __restrict__ apd1, unsigned short* __restrict__ apd2,
    unsigned short* __restrict__ apd3, unsigned short* __restrict__ embbf,
    float* __restrict__ hninit)
{
    int bid = blockIdx.x;
    if (bid < 7265) {
        // ---- halo zeroing ----
        int t = bid * 256 + threadIdx.x;
        unsigned int base, Hp, Wp, Cd, r;
        if (t < 528384)        { base = 0u;        Hp = 130; Wp = 130; Cd = 16; r = t; }
        else if (t < 1060864)  { base = 17305600u; Hp = 66;  Wp = 66;  Cd = 32; r = t - 528384; }
        else if (t < 1593344)  { base = 34615296u; Hp = 66;  Wp = 66;  Cd = 32; r = t - 1060864; }
        else if (t < 1859584)  { base = 43536384u; Hp = 66;  Wp = 66;  Cd = 16; r = t - 1593344; }
        else return;
        unsigned int perim = 2u * Wp + 2u * (Hp - 2u);
        unsigned int per_img = perim * Cd;
        unsigned int img = r / per_img, q = r % per_img;
        unsigned int p = q / Cd, c = q % Cd;
        unsigned int row, col;
        if (p < Wp)            { row = 0;      col = p; }
        else if (p < 2u * Wp)  { row = Hp - 1; col = p - Wp; }
        else { unsigned int s = p - 2u * Wp; row = 1 + (s >> 1); col = (s & 1) ? (Wp - 1) : 0; }
        ws_dw[base + ((img * Hp + row) * Wp + col) * Cd + c] = 0u;
        return;
    }
    // ---- weight prep ----
    int f = (bid - 7265) * 256 + threadIdx.x;
    if (f < 4096) {                               // e2
        int ks = f >> 8, mt = (f >> 6) & 3, lane = f & 63;
        int quad = lane >> 4, l16 = lane & 15;
        int oc = mt * 16 + l16, kh = ks >> 2, kw = ks & 3;
        short8 sv;
#pragma unroll
        for (int j = 0; j < 8; j++) {
            int ic = quad * 8 + j;
            sv[j] = (short)f2bf(e2w[((oc * 32 + ic) * 4 + kh) * 4 + kw]);
        }
        ((short8*)ape2)[f] = sv;
    } else if (f < 8704) {                        // e3
        int g = f - 4096;
        int ks = g >> 8, mt = (g >> 6) & 3, lane = g & 63;
        int quad = lane >> 4, l16 = lane & 15;
        int oc = mt * 16 + l16, tap = ks >> 1, kh = tap / 3, kw = tap % 3;
        int icb = (ks & 1) * 32 + quad * 8;
        short8 sv;
#pragma unroll
        for (int j = 0; j < 8; j++)
            sv[j] = (short)f2bf(e3w[((oc * 64 + icb + j) * 3 + kh) * 3 + kw]);
        ((short8*)ape3)[g] = sv;
    } else if (f < 11008) {                       // d1 (flipped)
        int g = f - 8704;
        int ks = g >> 7, mt = (g >> 6) & 1, lane = g & 63;
        int quad = lane >> 4, l16 = lane & 15;
        int oc = mt * 16 + l16, tap = ks >> 1, kh = tap / 3, kw = tap % 3;
        int icb = (ks & 1) * 32 + quad * 8;
        short8 sv;
#pragma unroll
        for (int j = 0; j < 8; j++)
            sv[j] = (short)f2bf(d1w[(((icb + j) * 32 + oc) * 3 + (2 - kh)) * 3 + (2 - kw)]);
        ((short8*)apd1)[g] = sv;
    } else if (f < 15104) {                       // d2 per parity
        int g = f - 11008;
        int par = g >> 10, ks = (g >> 8) & 3, mt = (g >> 6) & 3, lane = g & 63;
        int quad = lane >> 4, l16 = lane & 15;
        int ph = par >> 1, pw = par & 1, a = ks >> 1, bb = ks & 1;
        int kh = 3 - ph - 2 * a, kw = 3 - pw - 2 * bb;
        int oc = mt * 16 + l16;
        short8 sv;
#pragma unroll
        for (int j = 0; j < 8; j++) {
            int ic = quad * 8 + j;
            sv[j] = (short)f2bf(d2w[((ic * 64 + oc) * 4 + kh) * 4 + kw]);
        }
        ((short8*)apd2)[g] = sv;
    } else if (f < 15232) {                       // d3: A[tap][ic]
        int g = f - 15104;
        int ks = g >> 6, lane = g & 63;
        int quad = lane >> 4, tap = lane & 15;
        short8 sv;
#pragma unroll
        for (int j = 0; j < 8; j++) {
            int ic = ks * 32 + quad * 8 + j;
            sv[j] = (short)f2bf(d3w[ic * 16 + tap]);
        }
        ((short8*)apd3)[g] = sv;
    } else if (f < 19328) {                       // emb bf16
        int g = f - 15232;
        int code = g >> 3, chb = (g & 7) * 8;
        short8 sv;
#pragma unroll
        for (int j = 0; j < 8; j++) sv[j] = (short)f2bf(emb[code * 64 + chb + j]);
        ((short8*)embbf)[g] = sv;
    } else if (f < 19840) {                       // hninit = 2 - 0.5||e||^2
        int code = f - 19328;
        float s = 0.f;
        for (int c = 0; c < 64; c++) { float v = emb[code * 64 + c]; s += v * v; }
        hninit[code] = 2.0f - 0.5f * s;
    }
}

// ---------------- e1 (fp32 VALU) ----------------
__global__ __launch_bounds__(256) void k_e1(const float* __restrict__ x,
                                            const float* __restrict__ w,
                                            const float* __restrict__ b,
                                            unsigned short* __restrict__ h1p) {
    int idx = blockIdx.x * 256 + threadIdx.x;
    int ow = idx & 127, oh = (idx >> 7) & 127, n = idx >> 14;
    const float* xn = x + (size_t)n * 65536;
    float patch[16];
#pragma unroll
    for (int kh = 0; kh < 4; kh++) {
        int ih = 2 * oh + kh - 1;
#pragma unroll
        for (int kw = 0; kw < 4; kw++) {
            int iw = 2 * ow + kw - 1;
            bool ok = ((unsigned)ih < 256u) & ((unsigned)iw < 256u);
            patch[kh * 4 + kw] = ok ? xn[ih * 256 + iw] : 0.f;
        }
    }
    unsigned int outw[16];
#pragma unroll
    for (int oc = 0; oc < 32; oc++) {
        float acc = b[oc];
#pragma unroll
        for (int t = 0; t < 16; t++) acc += patch[t] * w[oc * 16 + t];
        unsigned short bf = f2bf(fmaxf(acc, 0.f));
        if (oc & 1) outw[oc >> 1] |= ((unsigned int)bf) << 16;
        else        outw[oc >> 1] = bf;
    }
    size_t base = (size_t)n * 540800 + ((oh + 1) * 130 + ow + 1) * 32;
    uint4* dst = (uint4*)(h1p + base);
#pragma unroll
    for (int i = 0; i < 4; i++) dst[i] = *(uint4*)&outw[i * 4];
}

// ---------------- MFMA implicit-GEMM conv; optional M-split (MS blocks per row-group) ----------------
// MODE 0: e2   1: e3 (ze fp32 + zeN)   2: d1
template<int CIN, int COUT, int MS, int KSTEPS, int WPIN, int STRIDE, int MODE>
__global__ __launch_bounds__(256) void k_conv(const unsigned short* __restrict__ inp,
                                              const unsigned short* __restrict__ aprep,
                                              const float* __restrict__ bias,
                                              unsigned short* __restrict__ out0,
                                              float* __restrict__ out1,
                                              unsigned short* __restrict__ out2) {
    constexpr int MTF = COUT / 16;
    constexpr int MT = MTF / MS;
    constexpr int MSB = (MS == 2) ? 1 : 0;
    constexpr int IMG = WPIN * WPIN * CIN;
    __shared__ short8 sA[KSTEPS * MT * 64];
    int tid = threadIdx.x;
    int wave = tid >> 6, lane = tid & 63, quad = lane >> 4, l16 = lane & 15;
    int bid = blockIdx.x;
    int ms = bid & (MS - 1);
    int rg = (bid >> MSB) & 15;
    int n = bid >> (4 + MSB);
    int oh = rg * 4 + wave;

    for (int i = tid; i < KSTEPS * MT * 64; i += 256) {
        int frag = i >> 6, lane_i = i & 63;
        int k = frag / MT, mt = frag - k * MT;
        sA[i] = ((const short8*)aprep)[(k * MTF + ms * MT + mt) * 64 + lane_i];
    }
    __syncthreads();

    int base0 = n * IMG + ((STRIDE * oh + 1) * WPIN + 1) * CIN + quad * 8;

    f32x4 acc[4][MT];
#pragma unroll
    for (int t = 0; t < 4; t++)
#pragma unroll
        for (int mt = 0; mt < MT; mt++)
            acc[t][mt] = *(const f32x4*)(bias + ms * MT * 16 + mt * 16 + quad * 4);

#pragma unroll
    for (int ks = 0; ks < KSTEPS; ks++) {
        int tap = (CIN == 64) ? (ks >> 1) : ks;
        int off;
        if (MODE == 0) { int kh = tap >> 2, kw = tap & 3; off = ((kh - 1) * WPIN + (kw - 1)) * CIN; }
        else           { int kh = tap / 3, kw = tap % 3;  off = ((kh - 1) * WPIN + (kw - 1)) * CIN; }
        int icsel = (CIN == 64) ? ((ks & 1) * 32) : 0;
        short8 bfr[4];
#pragma unroll
        for (int t = 0; t < 4; t++) {
            int ow = t * 16 + l16;
            bfr[t] = *(const short8*)(inp + base0 + STRIDE * ow * CIN + off + icsel);
        }
#pragma unroll
        for (int mt = 0; mt < MT; mt++) {
            short8 a = sA[(ks * MT + mt) * 64 + lane];
#pragma unroll
            for (int t = 0; t < 4; t++)
                acc[t][mt] = __builtin_amdgcn_mfma_f32_16x16x32_bf16(a, bfr[t], acc[t][mt], 0, 0, 0);
        }
    }

#pragma unroll
    for (int t = 0; t < 4; t++) {
        int ow = t * 16 + l16;
#pragma unroll
        for (int mt = 0; mt < MT; mt++) {
            float v0 = fmaxf(acc[t][mt][0], 0.f), v1 = fmaxf(acc[t][mt][1], 0.f);
            float v2 = fmaxf(acc[t][mt][2], 0.f), v3 = fmaxf(acc[t][mt][3], 0.f);
            unsigned int lo = (unsigned int)f2bf(v0) | ((unsigned int)f2bf(v1) << 16);
            unsigned int hi = (unsigned int)f2bf(v2) | ((unsigned int)f2bf(v3) << 16);
            uint2 uu; uu.x = lo; uu.y = hi;
            int oc = ms * MT * 16 + mt * 16 + quad * 4;
            if (MODE == 0) {
                size_t addr = (size_t)n * 278784 + ((oh + 1) * 66 + ow + 1) * 64 + oc;
                *(uint2*)(out0 + addr) = uu;
            } else if (MODE == 1) {
                int px = oh * 64 + ow;
                out1[((size_t)n * 64 + oc + 0) * 4096 + px] = v0;
                out1[((size_t)n * 64 + oc + 1) * 4096 + px] = v1;
                out1[((size_t)n * 64 + oc + 2) * 4096 + px] = v2;
                out1[((size_t)n * 64 + oc + 3) * 4096 + px] = v3;
                size_t addr = ((size_t)n * 4096 + px) * 64 + oc;
                *(uint2*)(out2 + addr) = uu;
            } else {
                size_t addr = (size_t)n * 139392 + ((oh + 1) * 66 + ow + 1) * 32 + oc;
                *(uint2*)(out0 + addr) = uu;
            }
        }
    }
}

// ---------------- VQ: LDS codebook, packed-key argmax; 512 threads / 8 waves ----------------
__global__ __launch_bounds__(512) void k_vq(const unsigned short* __restrict__ zeN,
                                            const unsigned short* __restrict__ embbf,
                                            const float* __restrict__ hninit,
                                            float* __restrict__ zq_out,
                                            unsigned short* __restrict__ zqp) {
    __shared__ short8 semb[4096];                  // 64 KB codebook
    int tid = threadIdx.x;
    int wave = tid >> 6, lane = tid & 63, quad = lane >> 4, l16 = lane & 15;
    for (int i = tid; i < 4096; i += 512) semb[i] = ((const short8*)embbf)[i];
    __syncthreads();

    int pxb = blockIdx.x * 512 + wave * 64;        // grid 512: 512*512 = 262144 px exactly
    short8 b0[4], b1[4];
#pragma unroll
    for (int t = 0; t < 4; t++) {
        int px = pxb + t * 16 + l16;
        b0[t] = *(const short8*)(zeN + (size_t)px * 64 + quad * 8);
        b1[t] = *(const short8*)(zeN + (size_t)px * 64 + 32 + quad * 8);
    }
    unsigned int bk[4] = {0u, 0u, 0u, 0u};
#pragma unroll 4
    for (int j0 = 0; j0 < 512; j0 += 16) {
        short8 a0 = semb[(j0 + l16) * 8 + quad];
        short8 a1 = semb[(j0 + l16) * 8 + 4 + quad];
        f32x4 ci = *(const f32x4*)(hninit + j0 + quad * 4);
        int iv = 511 - j0 - quad * 4;
#pragma unroll
        for (int t = 0; t < 4; t++) {
            f32x4 s = __builtin_amdgcn_mfma_f32_16x16x32_bf16(a0, b0[t], ci, 0, 0, 0);
            s = __builtin_amdgcn_mfma_f32_16x16x32_bf16(a1, b1[t], s, 0, 0, 0);
#pragma unroll
            for (int r = 0; r < 4; r++) {
                unsigned int key = (__float_as_uint(s[r]) & 0xFFFFFE00u) | (unsigned int)(iv - r);
                bk[t] = bk[t] > key ? bk[t] : key;
            }
        }
    }
#pragma unroll
    for (int t = 0; t < 4; t++) {
        unsigned int o1 = (unsigned int)__shfl_xor((int)bk[t], 16);
        bk[t] = bk[t] > o1 ? bk[t] : o1;
        unsigned int o2 = (unsigned int)__shfl_xor((int)bk[t], 32);
        bk[t] = bk[t] > o2 ? bk[t] : o2;
    }
#pragma unroll
    for (int t = 0; t < 4; t++) {
        int code = 511 - (int)(bk[t] & 511u);
        int px = pxb + t * 16 + l16;
        int n = px >> 12, hw = px & 4095, h = hw >> 6, w = hw & 63;
        uint4 u0 = *(const uint4*)&semb[code * 8 + quad * 2];
        uint4 u1 = *(const uint4*)&semb[code * 8 + quad * 2 + 1];
        size_t qaddr = (size_t)n * 278784 + ((h + 1) * 66 + (w + 1)) * 64 + quad * 16;
        *(uint4*)(zqp + qaddr) = u0;
        *(uint4*)(zqp + qaddr + 8) = u1;
        // zq fp32 reconstructed from bf16 codebook (err <= 8e-6, far under threshold)
        size_t zb = ((size_t)n * 64 + quad * 16) * 4096 + hw;
        unsigned int uw[8] = {u0.x, u0.y, u0.z, u0.w, u1.x, u1.y, u1.z, u1.w};
#pragma unroll
        for (int i = 0; i < 8; i++) {
            zq_out[zb + (2 * i + 0) * 4096] = __uint_as_float(uw[i] << 16);
            zq_out[zb + (2 * i + 1) * 4096] = __uint_as_float(uw[i] & 0xFFFF0000u);
        }
    }
}

// ---------------- d2 fused with d3 tap-score GEMM ----------------
__global__ __launch_bounds__(256) void k_d2f(const unsigned short* __restrict__ d1op,
                                             const unsigned short* __restrict__ apd2,
                                             const float* __restrict__ bias,
                                             const unsigned short* __restrict__ apd3,
                                             float* __restrict__ score) {
    __shared__ short8 sA[1024];                    // 16 KB (one parity's A)
    __shared__ short  sT[16384];                   // 32 KB transform (8 KB/wave)
    int tid = threadIdx.x;
    int wave = tid >> 6, lane = tid & 63, quad = lane >> 4, l16 = lane & 15;
    int bid = blockIdx.x;
    int n = bid >> 6, par = (bid >> 4) & 3, rg = bid & 15;
    int oh = rg * 4 + wave;
    int ph = par >> 1, pw = par & 1;

    for (int i = tid; i < 1024; i += 256) sA[i] = ((const short8*)apd2)[par * 1024 + i];
    __syncthreads();

    int base0 = n * 139392 + ((oh + ph) * 66 + pw) * 32 + quad * 8;
    f32x4 acc[4][4];
#pragma unroll
    for (int t = 0; t < 4; t++)
#pragma unroll
        for (int mt = 0; mt < 4; mt++)
            acc[t][mt] = *(const f32x4*)(bias + mt * 16 + quad * 4);

#pragma unroll
    for (int k = 0; k < 4; k++) {
        int a_ = k >> 1, bb = k & 1;
        int off = (a_ * 66 + bb) * 32;
        short8 bfr[4];
#pragma unroll
        for (int t = 0; t < 4; t++)
            bfr[t] = *(const short8*)(d1op + base0 + (t * 16 + l16) * 32 + off);
#pragma unroll
        for (int mt = 0; mt < 4; mt++) {
            short8 a = sA[(k * 4 + mt) * 64 + lane];
#pragma unroll
            for (int t = 0; t < 4; t++)
                acc[t][mt] = __builtin_amdgcn_mfma_f32_16x16x32_bf16(a, bfr[t], acc[t][mt], 0, 0, 0);
        }
    }
    // relu -> bf16 -> LDS (pixel-major)
#pragma unroll
    for (int t = 0; t < 4; t++) {
#pragma unroll
        for (int mt = 0; mt < 4; mt++) {
            float v0 = fmaxf(acc[t][mt][0], 0.f), v1 = fmaxf(acc[t][mt][1], 0.f);
            float v2 = fmaxf(acc[t][mt][2], 0.f), v3 = fmaxf(acc[t][mt][3], 0.f);
            uint2 uu;
            uu.x = (unsigned int)f2bf(v0) | ((unsigned int)f2bf(v1) << 16);
            uu.y = (unsigned int)f2bf(v2) | ((unsigned int)f2bf(v3) << 16);
            int addr = wave * 4096 + (t * 16 + l16) * 64 + mt * 16 + quad * 4;
            *(uint2*)&sT[addr] = uu;
        }
    }
    __syncthreads();
    // project onto 16 d3 taps and write scores
    short8 pa0 = ((const short8*)apd3)[lane];
    short8 pa1 = ((const short8*)apd3)[64 + lane];
#pragma unroll
    for (int t = 0; t < 4; t++) {
        const short* pbase = &sT[wave * 4096 + (t * 16 + l16) * 64];
        short8 pb0 = *(const short8*)(pbase + quad * 8);
        short8 pb1 = *(const short8*)(pbase + 32 + quad * 8);
        f32x4 sc = {0.f, 0.f, 0.f, 0.f};
        sc = __builtin_amdgcn_mfma_f32_16x16x32_bf16(pa0, pb0, sc, 0, 0, 0);
        sc = __builtin_amdgcn_mfma_f32_16x16x32_bf16(pa1, pb1, sc, 0, 0, 0);
        int oh_out = 2 * oh + ph, ow_out = 2 * (t * 16 + l16) + pw;
        *(f32x4*)(score + (((size_t)n * 128 + oh_out) * 128 + ow_out) * 16 + quad * 4) = sc;
    }
}

// ---------------- d3 epilogue: gather 4 taps ----------------
__global__ __launch_bounds__(256) void k_d3e(const float* __restrict__ scores,
                                             const float* __restrict__ d3b,
                                             float* __restrict__ xhat) {
    int idx = blockIdx.x * 256 + threadIdx.x;
    int ow = idx & 255, oh = (idx >> 8) & 255, n = idx >> 16;
    float acc = d3b[0];
    int kh0 = (oh + 1) & 1, kw0 = (ow + 1) & 1;
#pragma unroll
    for (int dh = 0; dh < 2; dh++) {
        int kh = kh0 + 2 * dh;
        int ih = (oh + 1 - kh) >> 1;
        bool vh = ((unsigned)ih < 128u);
#pragma unroll
        for (int dw = 0; dw < 2; dw++) {
            int kw = kw0 + 2 * dw;
            int iw = (ow + 1 - kw) >> 1;
            if (vh && ((unsigned)iw < 128u))
                acc += scores[(((size_t)n * 128 + ih) * 128 + iw) * 16 + kh * 4 + kw];
        }
    }
    xhat[(size_t)n * 65536 + oh * 256 + ow] = acc;
}

extern "C" void kernel_launch(void* const* d_in, const int* in_sizes, int n_in,
                              void* d_out, int out_size, void* d_ws, size_t ws_size,
                              hipStream_t stream) {
    const float* x    = (const float*)d_in[0];
    const float* e1w  = (const float*)d_in[1];
    const float* e1b  = (const float*)d_in[2];
    const float* e2w  = (const float*)d_in[3];
    const float* e2b  = (const float*)d_in[4];
    const float* e3w  = (const float*)d_in[5];
    const float* e3b  = (const float*)d_in[6];
    const float* emb  = (const float*)d_in[7];
    const float* d1w  = (const float*)d_in[8];
    const float* d1b  = (const float*)d_in[9];
    const float* d2w  = (const float*)d_in[10];
    const float* d2b  = (const float*)d_in[11];
    const float* d3w  = (const float*)d_in[12];
    const float* d3b  = (const float*)d_in[13];

    float* xhat = (float*)d_out;
    float* ze   = xhat + 4194304;
    float* zq   = ze + 16777216;

    char* ws = (char*)d_ws;
    unsigned short* h1p    = (unsigned short*)(ws + 0);
    unsigned short* h2p    = (unsigned short*)(ws + 69222400);
    unsigned short* zeN    = (unsigned short*)(ws + 104906752);
    unsigned short* zqp    = (unsigned short*)(ws + 138461184);
    unsigned short* d1op   = (unsigned short*)(ws + 174145536);
    float*          score  = (float*)(ws + 191987712);
    unsigned short* ape2   = (unsigned short*)(ws + 259096576);
    unsigned short* ape3   = (unsigned short*)(ws + 259162112);
    unsigned short* apd1   = (unsigned short*)(ws + 259235840);
    unsigned short* apd2   = (unsigned short*)(ws + 259272704);
    unsigned short* apd3   = (unsigned short*)(ws + 259338240);
    unsigned short* embbf  = (unsigned short*)(ws + 259340288);
    float*          hninit = (float*)(ws + 259405824);

    k_init<<<7343, 256, 0, stream>>>((unsigned int*)d_ws, e2w, e3w, d1w, d2w, d3w, emb,
                                     ape2, ape3, apd1, apd2, apd3, embbf, hninit);
    k_e1<<<4096, 256, 0, stream>>>(x, e1w, e1b, h1p);
    k_conv<32, 64, 2, 16, 130, 2, 0><<<2048, 256, 0, stream>>>(h1p, ape2, e2b, h2p, nullptr, nullptr);
    k_conv<64, 64, 2, 18, 66, 1, 1><<<2048, 256, 0, stream>>>(h2p, ape3, e3b, nullptr, ze, zeN);
    k_vq<<<512, 512, 0, stream>>>(zeN, embbf, hninit, zq, zqp);
    k_conv<64, 32, 1, 18, 66, 1, 2><<<1024, 256, 0, stream>>>(zqp, apd1, d1b, d1op, nullptr, nullptr);
    k_d2f<<<4096, 256, 0, stream>>>(d1op, apd2, d2b, apd3, score);
    k_d3e<<<16384, 256, 0, stream>>>(score, d3b, xhat);
}

// Round 6
// 432.098 us; speedup vs baseline: 1.2623x; 1.2623x over previous
//
#include <hip/hip_runtime.h>

typedef short short8 __attribute__((ext_vector_type(8)));
typedef float f32x4 __attribute__((ext_vector_type(4)));

__device__ __forceinline__ unsigned short f2bf(float f) {
    unsigned int u = __float_as_uint(f);
    u = (u + 0x7fffu + ((u >> 16) & 1u)) >> 16;
    return (unsigned short)u;
}
__device__ __forceinline__ float bf2f(unsigned short s) {
    return __uint_as_float(((unsigned int)s) << 16);
}

// ======== workspace byte offsets ========
// h1p2 : 0          (64,130,2,66,32) bf16  70,287,360 B  -- e1 out, parity-split cols
// h2p  : 70287360   (64,66,66,64)  bf16   35,684,352 B
// zeN  : 105971712  (64,64,64,64)  bf16   33,554,432 B
// zqp  : 139526144  (64,66,66,64)  bf16   35,684,352 B
// d1op : 175210496  (64,66,66,32)  bf16   17,842,176 B
// sc16 : 193052672  (16,64,128,128) bf16  33,554,432 B  -- tap-major d3 scores
// ape2 : 226607104  65536 ; ape3: 226672640 73728 ; apd1: 226746368 36864
// apd2 : 226783232  65536 ; apd3: 226848768 2048  ; embbf: 226850816 65536
// hninit: 226916352 2048

// ---------------- merged init: halo zeroing + weight prep ----------------
__global__ __launch_bounds__(256) void k_init(
    unsigned int* __restrict__ ws_dw,
    const float* __restrict__ e2w, const float* __restrict__ e3w,
    const float* __restrict__ d1w, const float* __restrict__ d2w,
    const float* __restrict__ d3w, const float* __restrict__ emb,
    unsigned short* __restrict__ ape2, unsigned short* __restrict__ ape3,
    unsigned short* __restrict__ apd1, unsigned short* __restrict__ apd2,
    unsigned short* __restrict__ apd3, unsigned short* __restrict__ embbf,
    float* __restrict__ hninit)
{
    int bid = blockIdx.x;
    if (bid < 7280) {
        int t = bid * 256 + threadIdx.x;
        if (t < 270336) {
            // h1p2 top/bottom rows (rows 0 and 129, both parity planes, idx 0..65)
            int img = t / 4224, q = t % 4224;
            int rowsel = q / 2112, rem = q % 2112;
            ws_dw[img * 274560 + rowsel * 129 * 2112 + rem] = 0u;
        } else if (t < 532480) {
            // h1p2 side cells: rows 1..128: odd plane idx0 (col -1), even plane idx64 (col 128)
            int g = t - 270336;
            int img = g / 4096, q = g % 4096;
            int row = 1 + (q >> 5), c2 = q & 31;
            int sel = c2 >> 4, ch = c2 & 15;          // sel0: par1 idx0 ; sel1: par0 idx64
            int par = sel ? 0 : 1, idx = sel ? 64 : 0;
            ws_dw[img * 274560 + row * 2112 + par * 1056 + idx * 16 + ch] = 0u;
        } else if (t < 1863680) {
            unsigned int base, Cd, r;
            if (t < 1064960)      { base = 17571840u; Cd = 32; r = t - 532480;  }   // h2p
            else if (t < 1597440) { base = 34881536u; Cd = 32; r = t - 1064960; }   // zqp
            else                  { base = 43802624u; Cd = 16; r = t - 1597440; }   // d1op
            unsigned int per_img = 260u * Cd;          // perim of 66x66
            unsigned int img = r / per_img, q = r % per_img;
            unsigned int p = q / Cd, c = q % Cd;
            unsigned int row, col;
            if (p < 66u)        { row = 0;  col = p; }
            else if (p < 132u)  { row = 65; col = p - 66u; }
            else { unsigned int s = p - 132u; row = 1 + (s >> 1); col = (s & 1) ? 65u : 0u; }
            ws_dw[base + ((img * 66u + row) * 66u + col) * Cd + c] = 0u;
        }
        return;
    }
    // ---- weight prep ----
    int f = (bid - 7280) * 256 + threadIdx.x;
    if (f < 4096) {                               // e2
        int ks = f >> 8, mt = (f >> 6) & 3, lane = f & 63;
        int quad = lane >> 4, l16 = lane & 15;
        int oc = mt * 16 + l16, kh = ks >> 2, kw = ks & 3;
        short8 sv;
#pragma unroll
        for (int j = 0; j < 8; j++) {
            int ic = quad * 8 + j;
            sv[j] = (short)f2bf(e2w[((oc * 32 + ic) * 4 + kh) * 4 + kw]);
        }
        ((short8*)ape2)[f] = sv;
    } else if (f < 8704) {                        // e3
        int g = f - 4096;
        int ks = g >> 8, mt = (g >> 6) & 3, lane = g & 63;
        int quad = lane >> 4, l16 = lane & 15;
        int oc = mt * 16 + l16, tap = ks >> 1, kh = tap / 3, kw = tap % 3;
        int icb = (ks & 1) * 32 + quad * 8;
        short8 sv;
#pragma unroll
        for (int j = 0; j < 8; j++)
            sv[j] = (short)f2bf(e3w[((oc * 64 + icb + j) * 3 + kh) * 3 + kw]);
        ((short8*)ape3)[g] = sv;
    } else if (f < 11008) {                       // d1 (flipped)
        int g = f - 8704;
        int ks = g >> 7, mt = (g >> 6) & 1, lane = g & 63;
        int quad = lane >> 4, l16 = lane & 15;
        int oc = mt * 16 + l16, tap = ks >> 1, kh = tap / 3, kw = tap % 3;
        int icb = (ks & 1) * 32 + quad * 8;
        short8 sv;
#pragma unroll
        for (int j = 0; j < 8; j++)
            sv[j] = (short)f2bf(d1w[(((icb + j) * 32 + oc) * 3 + (2 - kh)) * 3 + (2 - kw)]);
        ((short8*)apd1)[g] = sv;
    } else if (f < 15104) {                       // d2 per parity
        int g = f - 11008;
        int par = g >> 10, ks = (g >> 8) & 3, mt = (g >> 6) & 3, lane = g & 63;
        int quad = lane >> 4, l16 = lane & 15;
        int ph = par >> 1, pw = par & 1, a = ks >> 1, bb = ks & 1;
        int kh = 3 - ph - 2 * a, kw = 3 - pw - 2 * bb;
        int oc = mt * 16 + l16;
        short8 sv;
#pragma unroll
        for (int j = 0; j < 8; j++) {
            int ic = quad * 8 + j;
            sv[j] = (short)f2bf(d2w[((ic * 64 + oc) * 4 + kh) * 4 + kw]);
        }
        ((short8*)apd2)[g] = sv;
    } else if (f < 15232) {                       // d3: A[tap][ic]
        int g = f - 15104;
        int ks = g >> 6, lane = g & 63;
        int quad = lane >> 4, tap = lane & 15;
        short8 sv;
#pragma unroll
        for (int j = 0; j < 8; j++) {
            int ic = ks * 32 + quad * 8 + j;
            sv[j] = (short)f2bf(d3w[ic * 16 + tap]);
        }
        ((short8*)apd3)[g] = sv;
    } else if (f < 19328) {                       // emb bf16
        int g = f - 15232;
        int code = g >> 3, chb = (g & 7) * 8;
        short8 sv;
#pragma unroll
        for (int j = 0; j < 8; j++) sv[j] = (short)f2bf(emb[code * 64 + chb + j]);
        ((short8*)embbf)[g] = sv;
    } else if (f < 19840) {                       // hninit = 2 - 0.5||e||^2
        int code = f - 19328;
        float s = 0.f;
        for (int c = 0; c < 64; c++) { float v = emb[code * 64 + c]; s += v * v; }
        hninit[code] = 2.0f - 0.5f * s;
    }
}

// ---------------- e1 (fp32 VALU) -> parity-split padded NHWC bf16 ----------------
__global__ __launch_bounds__(256) void k_e1(const float* __restrict__ x,
                                            const float* __restrict__ w,
                                            const float* __restrict__ b,
                                            unsigned short* __restrict__ h1p2) {
    int idx = blockIdx.x * 256 + threadIdx.x;
    int ow = idx & 127, oh = (idx >> 7) & 127, n = idx >> 14;
    const float* xn = x + (size_t)n * 65536;
    float patch[16];
#pragma unroll
    for (int kh = 0; kh < 4; kh++) {
        int ih = 2 * oh + kh - 1;
#pragma unroll
        for (int kw = 0; kw < 4; kw++) {
            int iw = 2 * ow + kw - 1;
            bool ok = ((unsigned)ih < 256u) & ((unsigned)iw < 256u);
            patch[kh * 4 + kw] = ok ? xn[ih * 256 + iw] : 0.f;
        }
    }
    unsigned int outw[16];
#pragma unroll
    for (int oc = 0; oc < 32; oc++) {
        float acc = b[oc];
#pragma unroll
        for (int t = 0; t < 16; t++) acc += patch[t] * w[oc * 16 + t];
        unsigned short bf = f2bf(fmaxf(acc, 0.f));
        if (oc & 1) outw[oc >> 1] |= ((unsigned int)bf) << 16;
        else        outw[oc >> 1] = bf;
    }
    int par = ow & 1;
    int cidx = (ow + par) >> 1;                   // even col c -> c/2 ; odd col c -> (c+1)/2
    size_t base = ((size_t)(n * 130 + oh + 1) * 2 + par) * 2112 + cidx * 32;
    uint4* dst = (uint4*)(h1p2 + base);
#pragma unroll
    for (int i = 0; i < 4; i++) dst[i] = *(uint4*)&outw[i * 4];
}

// ---------------- MFMA implicit-GEMM conv (round-3 NCH-chunked structure) ----------------
// MODE 0: e2 (parity-split input)   1: e3 (ze fp32 + zeN)   2: d1
template<int CIN, int COUT, int KSTEPS, int NCH, int WPIN, int MODE>
__global__ __launch_bounds__(256) void k_conv(const unsigned short* __restrict__ inp,
                                              const unsigned short* __restrict__ aprep,
                                              const float* __restrict__ bias,
                                              unsigned short* __restrict__ out0,
                                              float* __restrict__ out1,
                                              unsigned short* __restrict__ out2) {
    constexpr int MT = COUT / 16;
    constexpr int KCH = KSTEPS / NCH;
    __shared__ short8 sA[KCH * MT * 64];
    int tid = threadIdx.x;
    int wave = tid >> 6, lane = tid & 63, quad = lane >> 4, l16 = lane & 15;
    int bid = blockIdx.x;
    int n = bid >> 4, rg = bid & 15;
    int oh = rg * 4 + wave;

    int base0;
    if (MODE == 0) base0 = (n * 130 + 2 * oh) * 4224 + quad * 8;            // parity-split
    else           base0 = n * (WPIN * WPIN * CIN) + ((oh + 1) * WPIN + 1) * CIN + quad * 8;

    f32x4 acc[4][MT];
#pragma unroll
    for (int t = 0; t < 4; t++)
#pragma unroll
        for (int mt = 0; mt < MT; mt++)
            acc[t][mt] = *(const f32x4*)(bias + mt * 16 + quad * 4);

#pragma unroll
    for (int ch = 0; ch < NCH; ch++) {
        for (int i = tid; i < KCH * MT * 64; i += 256)
            sA[i] = ((const short8*)aprep)[ch * (KCH * MT * 64) + i];
        __syncthreads();
#pragma unroll
        for (int k = 0; k < KCH; k++) {
            int ks = ch * KCH + k;
            int off, pxs;
            if (MODE == 0) {
                int kh = ks >> 2, kw = ks & 3;
                int par = (kw & 1) ^ 1;
                off = kh * 4224 + par * 2112 + (kw >> 1) * 32;
                pxs = 32;
            } else {
                int tap = ks >> 1, kh = tap / 3, kw = tap % 3;
                off = ((kh - 1) * WPIN + (kw - 1)) * CIN + (ks & 1) * 32;
                pxs = CIN;
            }
            short8 bfr[4];
#pragma unroll
            for (int t = 0; t < 4; t++)
                bfr[t] = *(const short8*)(inp + base0 + (t * 16 + l16) * pxs + off);
#pragma unroll
            for (int mt = 0; mt < MT; mt++) {
                short8 a = sA[(k * MT + mt) * 64 + lane];
#pragma unroll
                for (int t = 0; t < 4; t++)
                    acc[t][mt] = __builtin_amdgcn_mfma_f32_16x16x32_bf16(a, bfr[t], acc[t][mt], 0, 0, 0);
            }
        }
        if (ch + 1 < NCH) __syncthreads();
    }

#pragma unroll
    for (int t = 0; t < 4; t++) {
        int ow = t * 16 + l16;
#pragma unroll
        for (int mt = 0; mt < MT; mt++) {
            float v0 = fmaxf(acc[t][mt][0], 0.f), v1 = fmaxf(acc[t][mt][1], 0.f);
            float v2 = fmaxf(acc[t][mt][2], 0.f), v3 = fmaxf(acc[t][mt][3], 0.f);
            unsigned int lo = (unsigned int)f2bf(v0) | ((unsigned int)f2bf(v1) << 16);
            unsigned int hi = (unsigned int)f2bf(v2) | ((unsigned int)f2bf(v3) << 16);
            uint2 uu; uu.x = lo; uu.y = hi;
            int oc = mt * 16 + quad * 4;
            if (MODE == 0) {
                size_t addr = (size_t)n * 278784 + ((oh + 1) * 66 + ow + 1) * 64 + oc;
                *(uint2*)(out0 + addr) = uu;
            } else if (MODE == 1) {
                int px = oh * 64 + ow;
                __builtin_nontemporal_store(v0, &out1[((size_t)n * 64 + oc + 0) * 4096 + px]);
                __builtin_nontemporal_store(v1, &out1[((size_t)n * 64 + oc + 1) * 4096 + px]);
                __builtin_nontemporal_store(v2, &out1[((size_t)n * 64 + oc + 2) * 4096 + px]);
                __builtin_nontemporal_store(v3, &out1[((size_t)n * 64 + oc + 3) * 4096 + px]);
                size_t addr = ((size_t)n * 4096 + px) * 64 + oc;
                *(uint2*)(out2 + addr) = uu;
            } else {
                size_t addr = (size_t)n * 139392 + ((oh + 1) * 66 + ow + 1) * 32 + oc;
                *(uint2*)(out0 + addr) = uu;
            }
        }
    }
}

// ---------------- VQ: LDS codebook, packed-key argmax; 512 threads ----------------
__global__ __launch_bounds__(512) void k_vq(const unsigned short* __restrict__ zeN,
                                            const unsigned short* __restrict__ embbf,
                                            const float* __restrict__ hninit,
                                            float* __restrict__ zq_out,
                                            unsigned short* __restrict__ zqp) {
    __shared__ short8 semb[4096];                  // 64 KB codebook
    int tid = threadIdx.x;
    int wave = tid >> 6, lane = tid & 63, quad = lane >> 4, l16 = lane & 15;
    for (int i = tid; i < 4096; i += 512) semb[i] = ((const short8*)embbf)[i];
    __syncthreads();

    int pxb = blockIdx.x * 512 + wave * 64;
    short8 b0[4], b1[4];
#pragma unroll
    for (int t = 0; t < 4; t++) {
        int px = pxb + t * 16 + l16;
        b0[t] = *(const short8*)(zeN + (size_t)px * 64 + quad * 8);
        b1[t] = *(const short8*)(zeN + (size_t)px * 64 + 32 + quad * 8);
    }
    unsigned int bk[4] = {0u, 0u, 0u, 0u};
#pragma unroll 4
    for (int j0 = 0; j0 < 512; j0 += 16) {
        short8 a0 = semb[(j0 + l16) * 8 + quad];
        short8 a1 = semb[(j0 + l16) * 8 + 4 + quad];
        f32x4 ci = *(const f32x4*)(hninit + j0 + quad * 4);
        int iv = 511 - j0 - quad * 4;
#pragma unroll
        for (int t = 0; t < 4; t++) {
            f32x4 s = __builtin_amdgcn_mfma_f32_16x16x32_bf16(a0, b0[t], ci, 0, 0, 0);
            s = __builtin_amdgcn_mfma_f32_16x16x32_bf16(a1, b1[t], s, 0, 0, 0);
#pragma unroll
            for (int r = 0; r < 4; r++) {
                unsigned int key = (__float_as_uint(s[r]) & 0xFFFFFE00u) | (unsigned int)(iv - r);
                bk[t] = bk[t] > key ? bk[t] : key;
            }
        }
    }
#pragma unroll
    for (int t = 0; t < 4; t++) {
        unsigned int o1 = (unsigned int)__shfl_xor((int)bk[t], 16);
        bk[t] = bk[t] > o1 ? bk[t] : o1;
        unsigned int o2 = (unsigned int)__shfl_xor((int)bk[t], 32);
        bk[t] = bk[t] > o2 ? bk[t] : o2;
    }
#pragma unroll
    for (int t = 0; t < 4; t++) {
        int code = 511 - (int)(bk[t] & 511u);
        int px = pxb + t * 16 + l16;
        int n = px >> 12, hw = px & 4095, h = hw >> 6, w = hw & 63;
        uint4 u0 = *(const uint4*)&semb[code * 8 + quad * 2];
        uint4 u1 = *(const uint4*)&semb[code * 8 + quad * 2 + 1];
        size_t qaddr = (size_t)n * 278784 + ((h + 1) * 66 + (w + 1)) * 64 + quad * 16;
        *(uint4*)(zqp + qaddr) = u0;
        *(uint4*)(zqp + qaddr + 8) = u1;
        size_t zb = ((size_t)n * 64 + quad * 16) * 4096 + hw;
        unsigned int uw[8] = {u0.x, u0.y, u0.z, u0.w, u1.x, u1.y, u1.z, u1.w};
#pragma unroll
        for (int i = 0; i < 8; i++) {
            __builtin_nontemporal_store(__uint_as_float(uw[i] << 16), &zq_out[zb + (2 * i + 0) * 4096]);
            __builtin_nontemporal_store(__uint_as_float(uw[i] & 0xFFFF0000u), &zq_out[zb + (2 * i + 1) * 4096]);
        }
    }
}

// ---------------- d2 fused with d3 tap-score GEMM; tap-major bf16 scores ----------------
__global__ __launch_bounds__(256) void k_d2f(const unsigned short* __restrict__ d1op,
                                             const unsigned short* __restrict__ apd2,
                                             const float* __restrict__ bias,
                                             const unsigned short* __restrict__ apd3,
                                             unsigned short* __restrict__ sc16) {
    __shared__ short8 sA[1024];                    // 16 KB (one parity's A)
    __shared__ short  sT[4 * 64 * 72];             // 36.9 KB, px stride 72 (pad: no bank conflict)
    int tid = threadIdx.x;
    int wave = tid >> 6, lane = tid & 63, quad = lane >> 4, l16 = lane & 15;
    int bid = blockIdx.x;
    int n = bid >> 6, par = (bid >> 4) & 3, rg = bid & 15;
    int oh = rg * 4 + wave;
    int ph = par >> 1, pw = par & 1;

    for (int i = tid; i < 1024; i += 256) sA[i] = ((const short8*)apd2)[par * 1024 + i];
    __syncthreads();

    int base0 = n * 139392 + ((oh + ph) * 66 + pw) * 32 + quad * 8;
    f32x4 acc[4][4];
#pragma unroll
    for (int t = 0; t < 4; t++)
#pragma unroll
        for (int mt = 0; mt < 4; mt++)
            acc[t][mt] = *(const f32x4*)(bias + mt * 16 + quad * 4);

#pragma unroll
    for (int k = 0; k < 4; k++) {
        int a_ = k >> 1, bb = k & 1;
        int off = (a_ * 66 + bb) * 32;
        short8 bfr[4];
#pragma unroll
        for (int t = 0; t < 4; t++)
            bfr[t] = *(const short8*)(d1op + base0 + (t * 16 + l16) * 32 + off);
#pragma unroll
        for (int mt = 0; mt < 4; mt++) {
            short8 a = sA[(k * 4 + mt) * 64 + lane];
#pragma unroll
            for (int t = 0; t < 4; t++)
                acc[t][mt] = __builtin_amdgcn_mfma_f32_16x16x32_bf16(a, bfr[t], acc[t][mt], 0, 0, 0);
        }
    }
    // relu -> bf16 -> LDS (pixel-major, padded stride 72)
#pragma unroll
    for (int t = 0; t < 4; t++) {
#pragma unroll
        for (int mt = 0; mt < 4; mt++) {
            float v0 = fmaxf(acc[t][mt][0], 0.f), v1 = fmaxf(acc[t][mt][1], 0.f);
            float v2 = fmaxf(acc[t][mt][2], 0.f), v3 = fmaxf(acc[t][mt][3], 0.f);
            uint2 uu;
            uu.x = (unsigned int)f2bf(v0) | ((unsigned int)f2bf(v1) << 16);
            uu.y = (unsigned int)f2bf(v2) | ((unsigned int)f2bf(v3) << 16);
            int addr = wave * 4608 + (t * 16 + l16) * 72 + mt * 16 + quad * 4;
            *(uint2*)&sT[addr] = uu;
        }
    }
    __syncthreads();
    // project onto 16 d3 taps, write tap-major bf16 scores
    short8 pa0 = ((const short8*)apd3)[lane];
    short8 pa1 = ((const short8*)apd3)[64 + lane];
    int oh_out = 2 * oh + ph;
#pragma unroll
    for (int t = 0; t < 4; t++) {
        const short* pbase = &sT[wave * 4608 + (t * 16 + l16) * 72];
        short8 pb0 = *(const short8*)(pbase + quad * 8);
        short8 pb1 = *(const short8*)(pbase + 32 + quad * 8);
        f32x4 sc = {0.f, 0.f, 0.f, 0.f};
        sc = __builtin_amdgcn_mfma_f32_16x16x32_bf16(pa0, pb0, sc, 0, 0, 0);
        sc = __builtin_amdgcn_mfma_f32_16x16x32_bf16(pa1, pb1, sc, 0, 0, 0);
        int ow_out = 2 * (t * 16 + l16) + pw;
        int pbaseo = n * 16384 + oh_out * 128 + ow_out;
#pragma unroll
        for (int r = 0; r < 4; r++) {
            int tap = quad * 4 + r;
            sc16[(size_t)tap * 1048576 + pbaseo] = f2bf(sc[r]);
        }
    }
}

// ---------------- d3 epilogue: gather 4 taps from tap-major bf16 planes ----------------
__global__ __launch_bounds__(256) void k_d3e(const unsigned short* __restrict__ sc16,
                                             const float* __restrict__ d3b,
                                             float* __restrict__ xhat) {
    int idx = blockIdx.x * 256 + threadIdx.x;
    int ow = idx & 255, oh = (idx >> 8) & 255, n = idx >> 16;
    float acc = d3b[0];
    int kh0 = (oh + 1) & 1, kw0 = (ow + 1) & 1;
#pragma unroll
    for (int dh = 0; dh < 2; dh++) {
        int kh = kh0 + 2 * dh;
        int ih = (oh + 1 - kh) >> 1;
        bool vh = ((unsigned)ih < 128u);
#pragma unroll
        for (int dw = 0; dw < 2; dw++) {
            int kw = kw0 + 2 * dw;
            int iw = (ow + 1 - kw) >> 1;
            if (vh && ((unsigned)iw < 128u))
                acc += bf2f(sc16[(size_t)(kh * 4 + kw) * 1048576 + n * 16384 + ih * 128 + iw]);
        }
    }
    __builtin_nontemporal_store(acc, &xhat[(size_t)n * 65536 + oh * 256 + ow]);
}

extern "C" void kernel_launch(void* const* d_in, const int* in_sizes, int n_in,
                              void* d_out, int out_size, void* d_ws, size_t ws_size,
                              hipStream_t stream) {
    const float* x    = (const float*)d_in[0];
    const float* e1w  = (const float*)d_in[1];
    const float* e1b  = (const float*)d_in[2];
    const float* e2w  = (const float*)d_in[3];
    const float* e2b  = (const float*)d_in[4];
    const float* e3w  = (const float*)d_in[5];
    const float* e3b  = (const float*)d_in[6];
    const float* emb  = (const float*)d_in[7];
    const float* d1w  = (const float*)d_in[8];
    const float* d1b  = (const float*)d_in[9];
    const float* d2w  = (const float*)d_in[10];
    const float* d2b  = (const float*)d_in[11];
    const float* d3w  = (const float*)d_in[12];
    const float* d3b  = (const float*)d_in[13];

    float* xhat = (float*)d_out;
    float* ze   = xhat + 4194304;
    float* zq   = ze + 16777216;

    char* ws = (char*)d_ws;
    unsigned short* h1p2   = (unsigned short*)(ws + 0);
    unsigned short* h2p    = (unsigned short*)(ws + 70287360);
    unsigned short* zeN    = (unsigned short*)(ws + 105971712);
    unsigned short* zqp    = (unsigned short*)(ws + 139526144);
    unsigned short* d1op   = (unsigned short*)(ws + 175210496);
    unsigned short* sc16   = (unsigned short*)(ws + 193052672);
    unsigned short* ape2   = (unsigned short*)(ws + 226607104);
    unsigned short* ape3   = (unsigned short*)(ws + 226672640);
    unsigned short* apd1   = (unsigned short*)(ws + 226746368);
    unsigned short* apd2   = (unsigned short*)(ws + 226783232);
    unsigned short* apd3   = (unsigned short*)(ws + 226848768);
    unsigned short* embbf  = (unsigned short*)(ws + 226850816);
    float*          hninit = (float*)(ws + 226916352);

    k_init<<<7358, 256, 0, stream>>>((unsigned int*)d_ws, e2w, e3w, d1w, d2w, d3w, emb,
                                     ape2, ape3, apd1, apd2, apd3, embbf, hninit);
    k_e1<<<4096, 256, 0, stream>>>(x, e1w, e1b, h1p2);
    k_conv<32, 64, 16, 2, 0, 0><<<1024, 256, 0, stream>>>(h1p2, ape2, e2b, h2p, nullptr, nullptr);
    k_conv<64, 64, 18, 2, 66, 1><<<1024, 256, 0, stream>>>(h2p, ape3, e3b, nullptr, ze, zeN);
    k_vq<<<512, 512, 0, stream>>>(zeN, embbf, hninit, zq, zqp);
    k_conv<64, 32, 18, 2, 66, 2><<<1024, 256, 0, stream>>>(zqp, apd1, d1b, d1op, nullptr, nullptr);
    k_d2f<<<4096, 256, 0, stream>>>(d1op, apd2, d2b, apd3, sc16);
    k_d3e<<<16384, 256, 0, stream>>>(sc16, d3b, xhat);
}

// Round 7
// 429.504 us; speedup vs baseline: 1.2699x; 1.0060x over previous
//
#include <hip/hip_runtime.h>

typedef short short8 __attribute__((ext_vector_type(8)));
typedef float f32x4 __attribute__((ext_vector_type(4)));

union U8 { short8 s8; unsigned int u[4]; };

__device__ __forceinline__ unsigned short f2bf(float f) {
    unsigned int u = __float_as_uint(f);
    u = (u + 0x7fffu + ((u >> 16) & 1u)) >> 16;
    return (unsigned short)u;
}
__device__ __forceinline__ float bf2f(unsigned short s) {
    return __uint_as_float(((unsigned int)s) << 16);
}

// ======== workspace byte offsets ========
// h1p2 : 0          (64,130,2,66,32) bf16  70,287,360 B  -- e1 out, parity-split cols
// h2p  : 70287360   (64,66,66,64)  bf16   35,684,352 B
// zqp  : 139526144  (64,66,66,64)  bf16   35,684,352 B
// d1op : 175210496  (64,66,66,32)  bf16   17,842,176 B
// sc16 : 193052672  (16,64,128,128) bf16  33,554,432 B  -- tap-major d3 scores
// ape2 : 226607104  65536 ; ape3: 226672640 73728 ; apd1: 226746368 36864
// apd2 : 226783232  65536 ; apd3: 226848768 2048  ; embbf: 226850816 65536
// hninit: 226916352 2048

// ---------------- e1 + halo zeroing + weight prep (single launch) ----------------
__global__ __launch_bounds__(256) void k_e1i(
    const float* __restrict__ x, const float* __restrict__ e1w, const float* __restrict__ e1b,
    unsigned short* __restrict__ h1p2, unsigned int* __restrict__ ws_dw,
    const float* __restrict__ e2w, const float* __restrict__ e3w,
    const float* __restrict__ d1w, const float* __restrict__ d2w,
    const float* __restrict__ d3w, const float* __restrict__ emb,
    unsigned short* __restrict__ ape2, unsigned short* __restrict__ ape3,
    unsigned short* __restrict__ apd1, unsigned short* __restrict__ apd2,
    unsigned short* __restrict__ apd3, unsigned short* __restrict__ embbf,
    float* __restrict__ hninit)
{
    int bid = blockIdx.x;
    if (bid < 4096) {
        // ---- e1 conv ----
        int idx = bid * 256 + threadIdx.x;
        int ow = idx & 127, oh = (idx >> 7) & 127, n = idx >> 14;
        const float* xn = x + (size_t)n * 65536;
        float patch[16];
#pragma unroll
        for (int kh = 0; kh < 4; kh++) {
            int ih = 2 * oh + kh - 1;
#pragma unroll
            for (int kw = 0; kw < 4; kw++) {
                int iw = 2 * ow + kw - 1;
                bool ok = ((unsigned)ih < 256u) & ((unsigned)iw < 256u);
                patch[kh * 4 + kw] = ok ? xn[ih * 256 + iw] : 0.f;
            }
        }
        unsigned int outw[16];
#pragma unroll
        for (int oc = 0; oc < 32; oc++) {
            float acc = e1b[oc];
#pragma unroll
            for (int t = 0; t < 16; t++) acc += patch[t] * e1w[oc * 16 + t];
            unsigned short bf = f2bf(fmaxf(acc, 0.f));
            if (oc & 1) outw[oc >> 1] |= ((unsigned int)bf) << 16;
            else        outw[oc >> 1] = bf;
        }
        int par = ow & 1;
        int cidx = (ow + par) >> 1;
        size_t base = ((size_t)((idx >> 14) * 130 + oh + 1) * 2 + par) * 2112 + cidx * 32;
        uint4* dst = (uint4*)(h1p2 + base);
#pragma unroll
        for (int i = 0; i < 4; i++) dst[i] = *(uint4*)&outw[i * 4];
        return;
    }
    if (bid < 11376) {
        // ---- halo zeroing ----
        int t = (bid - 4096) * 256 + threadIdx.x;
        if (t < 270336) {
            int img = t / 4224, q = t % 4224;
            int rowsel = q / 2112, rem = q % 2112;
            ws_dw[img * 274560 + rowsel * 129 * 2112 + rem] = 0u;
        } else if (t < 532480) {
            int g = t - 270336;
            int img = g / 4096, q = g % 4096;
            int row = 1 + (q >> 5), c2 = q & 31;
            int sel = c2 >> 4, ch = c2 & 15;
            int par = sel ? 0 : 1, idx2 = sel ? 64 : 0;
            ws_dw[img * 274560 + row * 2112 + par * 1056 + idx2 * 16 + ch] = 0u;
        } else if (t < 1863680) {
            unsigned int base, Cd, r;
            if (t < 1064960)      { base = 17571840u; Cd = 32; r = t - 532480;  }   // h2p
            else if (t < 1597440) { base = 34881536u; Cd = 32; r = t - 1064960; }   // zqp
            else                  { base = 43802624u; Cd = 16; r = t - 1597440; }   // d1op
            unsigned int per_img = 260u * Cd;
            unsigned int img = r / per_img, q = r % per_img;
            unsigned int p = q / Cd, c = q % Cd;
            unsigned int row, col;
            if (p < 66u)        { row = 0;  col = p; }
            else if (p < 132u)  { row = 65; col = p - 66u; }
            else { unsigned int s = p - 132u; row = 1 + (s >> 1); col = (s & 1) ? 65u : 0u; }
            ws_dw[base + ((img * 66u + row) * 66u + col) * Cd + c] = 0u;
        }
        return;
    }
    // ---- weight prep ----
    int f = (bid - 11376) * 256 + threadIdx.x;
    if (f < 4096) {                               // e2
        int ks = f >> 8, mt = (f >> 6) & 3, lane = f & 63;
        int quad = lane >> 4, l16 = lane & 15;
        int oc = mt * 16 + l16, kh = ks >> 2, kw = ks & 3;
        short8 sv;
#pragma unroll
        for (int j = 0; j < 8; j++) {
            int ic = quad * 8 + j;
            sv[j] = (short)f2bf(e2w[((oc * 32 + ic) * 4 + kh) * 4 + kw]);
        }
        ((short8*)ape2)[f] = sv;
    } else if (f < 8704) {                        // e3
        int g = f - 4096;
        int ks = g >> 8, mt = (g >> 6) & 3, lane = g & 63;
        int quad = lane >> 4, l16 = lane & 15;
        int oc = mt * 16 + l16, tap = ks >> 1, kh = tap / 3, kw = tap % 3;
        int icb = (ks & 1) * 32 + quad * 8;
        short8 sv;
#pragma unroll
        for (int j = 0; j < 8; j++)
            sv[j] = (short)f2bf(e3w[((oc * 64 + icb + j) * 3 + kh) * 3 + kw]);
        ((short8*)ape3)[g] = sv;
    } else if (f < 11008) {                       // d1 (flipped)
        int g = f - 8704;
        int ks = g >> 7, mt = (g >> 6) & 1, lane = g & 63;
        int quad = lane >> 4, l16 = lane & 15;
        int oc = mt * 16 + l16, tap = ks >> 1, kh = tap / 3, kw = tap % 3;
        int icb = (ks & 1) * 32 + quad * 8;
        short8 sv;
#pragma unroll
        for (int j = 0; j < 8; j++)
            sv[j] = (short)f2bf(d1w[(((icb + j) * 32 + oc) * 3 + (2 - kh)) * 3 + (2 - kw)]);
        ((short8*)apd1)[g] = sv;
    } else if (f < 15104) {                       // d2 per parity
        int g = f - 11008;
        int par = g >> 10, ks = (g >> 8) & 3, mt = (g >> 6) & 3, lane = g & 63;
        int quad = lane >> 4, l16 = lane & 15;
        int ph = par >> 1, pw = par & 1, a = ks >> 1, bb = ks & 1;
        int kh = 3 - ph - 2 * a, kw = 3 - pw - 2 * bb;
        int oc = mt * 16 + l16;
        short8 sv;
#pragma unroll
        for (int j = 0; j < 8; j++) {
            int ic = quad * 8 + j;
            sv[j] = (short)f2bf(d2w[((ic * 64 + oc) * 4 + kh) * 4 + kw]);
        }
        ((short8*)apd2)[g] = sv;
    } else if (f < 15232) {                       // d3: A[tap][ic]
        int g = f - 15104;
        int ks = g >> 6, lane = g & 63;
        int quad = lane >> 4, tap = lane & 15;
        short8 sv;
#pragma unroll
        for (int j = 0; j < 8; j++) {
            int ic = ks * 32 + quad * 8 + j;
            sv[j] = (short)f2bf(d3w[ic * 16 + tap]);
        }
        ((short8*)apd3)[g] = sv;
    } else if (f < 19328) {                       // emb bf16
        int g = f - 15232;
        int code = g >> 3, chb = (g & 7) * 8;
        short8 sv;
#pragma unroll
        for (int j = 0; j < 8; j++) sv[j] = (short)f2bf(emb[code * 64 + chb + j]);
        ((short8*)embbf)[g] = sv;
    } else if (f < 19840) {                       // hninit = 2 - 0.5||e||^2
        int code = f - 19328;
        float s = 0.f;
        for (int c = 0; c < 64; c++) { float v = emb[code * 64 + c]; s += v * v; }
        hninit[code] = 2.0f - 0.5f * s;
    }
}

// ---------------- MFMA implicit-GEMM conv ----------------
// MODE 0: e2 (parity-split input)   2: d1
template<int CIN, int COUT, int KSTEPS, int NCH, int WPIN, int MODE>
__global__ __launch_bounds__(256, 3) void k_conv(const unsigned short* __restrict__ inp,
                                                 const unsigned short* __restrict__ aprep,
                                                 const float* __restrict__ bias,
                                                 unsigned short* __restrict__ out0) {
    constexpr int MT = COUT / 16;
    constexpr int KCH = KSTEPS / NCH;
    __shared__ short8 sA[KCH * MT * 64];
    int tid = threadIdx.x;
    int wave = tid >> 6, lane = tid & 63, quad = lane >> 4, l16 = lane & 15;
    int bid = blockIdx.x;
    int n = bid >> 4, rg = bid & 15;
    int oh = rg * 4 + wave;

    int base0;
    if (MODE == 0) base0 = (n * 130 + 2 * oh) * 4224 + quad * 8;
    else           base0 = n * (WPIN * WPIN * CIN) + ((oh + 1) * WPIN + 1) * CIN + quad * 8;

    f32x4 acc[4][MT];
#pragma unroll
    for (int t = 0; t < 4; t++)
#pragma unroll
        for (int mt = 0; mt < MT; mt++)
            acc[t][mt] = *(const f32x4*)(bias + mt * 16 + quad * 4);

#pragma unroll
    for (int ch = 0; ch < NCH; ch++) {
        for (int i = tid; i < KCH * MT * 64; i += 256)
            sA[i] = ((const short8*)aprep)[ch * (KCH * MT * 64) + i];
        __syncthreads();
#pragma unroll
        for (int k = 0; k < KCH; k++) {
            int ks = ch * KCH + k;
            int off, pxs;
            if (MODE == 0) {
                int kh = ks >> 2, kw = ks & 3;
                int par = (kw & 1) ^ 1;
                off = kh * 4224 + par * 2112 + (kw >> 1) * 32;
                pxs = 32;
            } else {
                int tap = ks >> 1, kh = tap / 3, kw = tap % 3;
                off = ((kh - 1) * WPIN + (kw - 1)) * CIN + (ks & 1) * 32;
                pxs = CIN;
            }
            short8 bfr[4];
#pragma unroll
            for (int t = 0; t < 4; t++)
                bfr[t] = *(const short8*)(inp + base0 + (t * 16 + l16) * pxs + off);
#pragma unroll
            for (int mt = 0; mt < MT; mt++) {
                short8 a = sA[(k * MT + mt) * 64 + lane];
#pragma unroll
                for (int t = 0; t < 4; t++)
                    acc[t][mt] = __builtin_amdgcn_mfma_f32_16x16x32_bf16(a, bfr[t], acc[t][mt], 0, 0, 0);
            }
        }
        if (ch + 1 < NCH) __syncthreads();
    }

#pragma unroll
    for (int t = 0; t < 4; t++) {
        int ow = t * 16 + l16;
#pragma unroll
        for (int mt = 0; mt < MT; mt++) {
            float v0 = fmaxf(acc[t][mt][0], 0.f), v1 = fmaxf(acc[t][mt][1], 0.f);
            float v2 = fmaxf(acc[t][mt][2], 0.f), v3 = fmaxf(acc[t][mt][3], 0.f);
            unsigned int lo = (unsigned int)f2bf(v0) | ((unsigned int)f2bf(v1) << 16);
            unsigned int hi = (unsigned int)f2bf(v2) | ((unsigned int)f2bf(v3) << 16);
            uint2 uu; uu.x = lo; uu.y = hi;
            int oc = mt * 16 + quad * 4;
            if (MODE == 0) {
                size_t addr = (size_t)n * 278784 + ((oh + 1) * 66 + ow + 1) * 64 + oc;
                *(uint2*)(out0 + addr) = uu;
            } else {
                size_t addr = (size_t)n * 139392 + ((oh + 1) * 66 + ow + 1) * 32 + oc;
                *(uint2*)(out0 + addr) = uu;
            }
        }
    }
}

// ---------------- e3 conv fused with VQ (shfl transform, L2-streamed codebook) ----------------
__global__ __launch_bounds__(256, 3) void k_e3vq(const unsigned short* __restrict__ h2p,
                                                 const unsigned short* __restrict__ ape3,
                                                 const float* __restrict__ bias,
                                                 const unsigned short* __restrict__ embbf,
                                                 const float* __restrict__ hninit,
                                                 float* __restrict__ ze_out,
                                                 float* __restrict__ zq_out,
                                                 unsigned short* __restrict__ zqp) {
    __shared__ short8 sA[9 * 4 * 64];              // 36 KB
    int tid = threadIdx.x;
    int wave = tid >> 6, lane = tid & 63, quad = lane >> 4, l16 = lane & 15;
    int bid = blockIdx.x;
    int n = bid >> 4, rg = bid & 15;
    int oh = rg * 4 + wave;
    int base0 = n * 278784 + ((oh + 1) * 66 + 1) * 64 + quad * 8;

    f32x4 acc[4][4];
#pragma unroll
    for (int t = 0; t < 4; t++)
#pragma unroll
        for (int mt = 0; mt < 4; mt++)
            acc[t][mt] = *(const f32x4*)(bias + mt * 16 + quad * 4);

#pragma unroll
    for (int ch = 0; ch < 2; ch++) {
        for (int i = tid; i < 9 * 4 * 64; i += 256)
            sA[i] = ((const short8*)ape3)[ch * (9 * 4 * 64) + i];
        __syncthreads();
#pragma unroll
        for (int k = 0; k < 9; k++) {
            int ks = ch * 9 + k;
            int tap = ks >> 1, kh = tap / 3, kw = tap % 3;
            int off = ((kh - 1) * 66 + (kw - 1)) * 64 + (ks & 1) * 32;
            short8 bfr[4];
#pragma unroll
            for (int t = 0; t < 4; t++)
                bfr[t] = *(const short8*)(h2p + base0 + (t * 16 + l16) * 64 + off);
#pragma unroll
            for (int mt = 0; mt < 4; mt++) {
                short8 a = sA[(k * 4 + mt) * 64 + lane];
#pragma unroll
                for (int t = 0; t < 4; t++)
                    acc[t][mt] = __builtin_amdgcn_mfma_f32_16x16x32_bf16(a, bfr[t], acc[t][mt], 0, 0, 0);
            }
        }
        if (ch == 0) __syncthreads();
    }

    // relu in place
#pragma unroll
    for (int t = 0; t < 4; t++)
#pragma unroll
        for (int mt = 0; mt < 4; mt++)
#pragma unroll
            for (int r = 0; r < 4; r++)
                acc[t][mt][r] = fmaxf(acc[t][mt][r], 0.f);

    // ze fp32 NCHW (graded output), nontemporal
#pragma unroll
    for (int t = 0; t < 4; t++) {
        int px = oh * 64 + t * 16 + l16;
#pragma unroll
        for (int mt = 0; mt < 4; mt++) {
            int oc = mt * 16 + quad * 4;
#pragma unroll
            for (int r = 0; r < 4; r++)
                __builtin_nontemporal_store(acc[t][mt][r], &ze_out[((size_t)n * 64 + oc + r) * 4096 + px]);
        }
    }

    // in-register C-layout -> B-layout transform (8 shfl per tile)
    short8 b0[4], b1[4];
    int s0 = (((2 * quad) & 3) << 4) | l16;
    int s1 = (((2 * quad + 1) & 3) << 4) | l16;
#pragma unroll
    for (int t = 0; t < 4; t++) {
        f32x4 xv = (quad < 2) ? acc[t][0] : acc[t][1];
        f32x4 yv = (quad < 2) ? acc[t][2] : acc[t][3];
        unsigned int xa = (unsigned int)f2bf(xv[0]) | ((unsigned int)f2bf(xv[1]) << 16);
        unsigned int xb = (unsigned int)f2bf(xv[2]) | ((unsigned int)f2bf(xv[3]) << 16);
        unsigned int ya = (unsigned int)f2bf(yv[0]) | ((unsigned int)f2bf(yv[1]) << 16);
        unsigned int yb = (unsigned int)f2bf(yv[2]) | ((unsigned int)f2bf(yv[3]) << 16);
        U8 ub0, ub1;
        ub0.u[0] = (unsigned int)__shfl((int)xa, s0); ub0.u[1] = (unsigned int)__shfl((int)xb, s0);
        ub0.u[2] = (unsigned int)__shfl((int)xa, s1); ub0.u[3] = (unsigned int)__shfl((int)xb, s1);
        ub1.u[0] = (unsigned int)__shfl((int)ya, s0); ub1.u[1] = (unsigned int)__shfl((int)yb, s0);
        ub1.u[2] = (unsigned int)__shfl((int)ya, s1); ub1.u[3] = (unsigned int)__shfl((int)yb, s1);
        b0[t] = ub0.s8; b1[t] = ub1.s8;
    }

    // VQ: stream codebook from L2, packed-key argmax
    unsigned int bk[4] = {0u, 0u, 0u, 0u};
#pragma unroll 4
    for (int j0 = 0; j0 < 512; j0 += 16) {
        short8 a0 = *(const short8*)(embbf + (j0 + l16) * 64 + quad * 8);
        short8 a1 = *(const short8*)(embbf + (j0 + l16) * 64 + 32 + quad * 8);
        f32x4 ci = *(const f32x4*)(hninit + j0 + quad * 4);
        int iv = 511 - j0 - quad * 4;
#pragma unroll
        for (int t = 0; t < 4; t++) {
            f32x4 s = __builtin_amdgcn_mfma_f32_16x16x32_bf16(a0, b0[t], ci, 0, 0, 0);
            s = __builtin_amdgcn_mfma_f32_16x16x32_bf16(a1, b1[t], s, 0, 0, 0);
#pragma unroll
            for (int r = 0; r < 4; r++) {
                unsigned int key = (__float_as_uint(s[r]) & 0xFFFFFE00u) | (unsigned int)(iv - r);
                bk[t] = bk[t] > key ? bk[t] : key;
            }
        }
    }
#pragma unroll
    for (int t = 0; t < 4; t++) {
        unsigned int o1 = (unsigned int)__shfl_xor((int)bk[t], 16);
        bk[t] = bk[t] > o1 ? bk[t] : o1;
        unsigned int o2 = (unsigned int)__shfl_xor((int)bk[t], 32);
        bk[t] = bk[t] > o2 ? bk[t] : o2;
    }
#pragma unroll
    for (int t = 0; t < 4; t++) {
        int code = 511 - (int)(bk[t] & 511u);
        int col = t * 16 + l16;
        int hw = oh * 64 + col;
        uint4 u0 = *(const uint4*)(embbf + code * 64 + quad * 16);
        uint4 u1 = *(const uint4*)(embbf + code * 64 + quad * 16 + 8);
        size_t qaddr = (size_t)n * 278784 + ((oh + 1) * 66 + (col + 1)) * 64 + quad * 16;
        *(uint4*)(zqp + qaddr) = u0;
        *(uint4*)(zqp + qaddr + 8) = u1;
        size_t zb = ((size_t)n * 64 + quad * 16) * 4096 + hw;
        unsigned int uw[8] = {u0.x, u0.y, u0.z, u0.w, u1.x, u1.y, u1.z, u1.w};
#pragma unroll
        for (int i = 0; i < 8; i++) {
            __builtin_nontemporal_store(__uint_as_float(uw[i] << 16), &zq_out[zb + (2 * i + 0) * 4096]);
            __builtin_nontemporal_store(__uint_as_float(uw[i] & 0xFFFF0000u), &zq_out[zb + (2 * i + 1) * 4096]);
        }
    }
}

// ---------------- d2 fused with d3 tap-score GEMM (shfl transform, no sT) ----------------
__global__ __launch_bounds__(256, 3) void k_d2f(const unsigned short* __restrict__ d1op,
                                                const unsigned short* __restrict__ apd2,
                                                const float* __restrict__ bias,
                                                const unsigned short* __restrict__ apd3,
                                                unsigned short* __restrict__ sc16) {
    __shared__ short8 sA[1024];                    // 16 KB (one parity's A)
    int tid = threadIdx.x;
    int wave = tid >> 6, lane = tid & 63, quad = lane >> 4, l16 = lane & 15;
    int bid = blockIdx.x;
    int n = bid >> 6, par = (bid >> 4) & 3, rg = bid & 15;
    int oh = rg * 4 + wave;
    int ph = par >> 1, pw = par & 1;

    short8 pa0 = ((const short8*)apd3)[lane];
    short8 pa1 = ((const short8*)apd3)[64 + lane];

    for (int i = tid; i < 1024; i += 256) sA[i] = ((const short8*)apd2)[par * 1024 + i];
    __syncthreads();

    int base0 = n * 139392 + ((oh + ph) * 66 + pw) * 32 + quad * 8;
    f32x4 acc[4][4];
#pragma unroll
    for (int t = 0; t < 4; t++)
#pragma unroll
        for (int mt = 0; mt < 4; mt++)
            acc[t][mt] = *(const f32x4*)(bias + mt * 16 + quad * 4);

#pragma unroll
    for (int k = 0; k < 4; k++) {
        int a_ = k >> 1, bb = k & 1;
        int off = (a_ * 66 + bb) * 32;
        short8 bfr[4];
#pragma unroll
        for (int t = 0; t < 4; t++)
            bfr[t] = *(const short8*)(d1op + base0 + (t * 16 + l16) * 32 + off);
#pragma unroll
        for (int mt = 0; mt < 4; mt++) {
            short8 a = sA[(k * 4 + mt) * 64 + lane];
#pragma unroll
            for (int t = 0; t < 4; t++)
                acc[t][mt] = __builtin_amdgcn_mfma_f32_16x16x32_bf16(a, bfr[t], acc[t][mt], 0, 0, 0);
        }
    }

    // relu + in-register transform + tap projection
    int s0 = (((2 * quad) & 3) << 4) | l16;
    int s1 = (((2 * quad + 1) & 3) << 4) | l16;
    int oh_out = 2 * oh + ph;
#pragma unroll
    for (int t = 0; t < 4; t++) {
#pragma unroll
        for (int mt = 0; mt < 4; mt++)
#pragma unroll
            for (int r = 0; r < 4; r++)
                acc[t][mt][r] = fmaxf(acc[t][mt][r], 0.f);
        f32x4 xv = (quad < 2) ? acc[t][0] : acc[t][1];
        f32x4 yv = (quad < 2) ? acc[t][2] : acc[t][3];
        unsigned int xa = (unsigned int)f2bf(xv[0]) | ((unsigned int)f2bf(xv[1]) << 16);
        unsigned int xb = (unsigned int)f2bf(xv[2]) | ((unsigned int)f2bf(xv[3]) << 16);
        unsigned int ya = (unsigned int)f2bf(yv[0]) | ((unsigned int)f2bf(yv[1]) << 16);
        unsigned int yb = (unsigned int)f2bf(yv[2]) | ((unsigned int)f2bf(yv[3]) << 16);
        U8 ub0, ub1;
        ub0.u[0] = (unsigned int)__shfl((int)xa, s0); ub0.u[1] = (unsigned int)__shfl((int)xb, s0);
        ub0.u[2] = (unsigned int)__shfl((int)xa, s1); ub0.u[3] = (unsigned int)__shfl((int)xb, s1);
        ub1.u[0] = (unsigned int)__shfl((int)ya, s0); ub1.u[1] = (unsigned int)__shfl((int)yb, s0);
        ub1.u[2] = (unsigned int)__shfl((int)ya, s1); ub1.u[3] = (unsigned int)__shfl((int)yb, s1);
        f32x4 sc = {0.f, 0.f, 0.f, 0.f};
        sc = __builtin_amdgcn_mfma_f32_16x16x32_bf16(pa0, ub0.s8, sc, 0, 0, 0);
        sc = __builtin_amdgcn_mfma_f32_16x16x32_bf16(pa1, ub1.s8, sc, 0, 0, 0);
        int ow_out = 2 * (t * 16 + l16) + pw;
        int pbaseo = n * 16384 + oh_out * 128 + ow_out;
#pragma unroll
        for (int r = 0; r < 4; r++) {
            int tap = quad * 4 + r;
            sc16[(size_t)tap * 1048576 + pbaseo] = f2bf(sc[r]);
        }
    }
}

// ---------------- d3 epilogue: gather 4 taps from tap-major bf16 planes ----------------
__global__ __launch_bounds__(256) void k_d3e(const unsigned short* __restrict__ sc16,
                                             const float* __restrict__ d3b,
                                             float* __restrict__ xhat) {
    int idx = blockIdx.x * 256 + threadIdx.x;
    int ow = idx & 255, oh = (idx >> 8) & 255, n = idx >> 16;
    float acc = d3b[0];
    int kh0 = (oh + 1) & 1, kw0 = (ow + 1) & 1;
#pragma unroll
    for (int dh = 0; dh < 2; dh++) {
        int kh = kh0 + 2 * dh;
        int ih = (oh + 1 - kh) >> 1;
        bool vh = ((unsigned)ih < 128u);
#pragma unroll
        for (int dw = 0; dw < 2; dw++) {
            int kw = kw0 + 2 * dw;
            int iw = (ow + 1 - kw) >> 1;
            if (vh && ((unsigned)iw < 128u))
                acc += bf2f(sc16[(size_t)(kh * 4 + kw) * 1048576 + n * 16384 + ih * 128 + iw]);
        }
    }
    __builtin_nontemporal_store(acc, &xhat[(size_t)n * 65536 + oh * 256 + ow]);
}

extern "C" void kernel_launch(void* const* d_in, const int* in_sizes, int n_in,
                              void* d_out, int out_size, void* d_ws, size_t ws_size,
                              hipStream_t stream) {
    const float* x    = (const float*)d_in[0];
    const float* e1w  = (const float*)d_in[1];
    const float* e1b  = (const float*)d_in[2];
    const float* e2w  = (const float*)d_in[3];
    const float* e2b  = (const float*)d_in[4];
    const float* e3w  = (const float*)d_in[5];
    const float* e3b  = (const float*)d_in[6];
    const float* emb  = (const float*)d_in[7];
    const float* d1w  = (const float*)d_in[8];
    const float* d1b  = (const float*)d_in[9];
    const float* d2w  = (const float*)d_in[10];
    const float* d2b  = (const float*)d_in[11];
    const float* d3w  = (const float*)d_in[12];
    const float* d3b  = (const float*)d_in[13];

    float* xhat = (float*)d_out;
    float* ze   = xhat + 4194304;
    float* zq   = ze + 16777216;

    char* ws = (char*)d_ws;
    unsigned short* h1p2   = (unsigned short*)(ws + 0);
    unsigned short* h2p    = (unsigned short*)(ws + 70287360);
    unsigned short* zqp    = (unsigned short*)(ws + 139526144);
    unsigned short* d1op   = (unsigned short*)(ws + 175210496);
    unsigned short* sc16   = (unsigned short*)(ws + 193052672);
    unsigned short* ape2   = (unsigned short*)(ws + 226607104);
    unsigned short* ape3   = (unsigned short*)(ws + 226672640);
    unsigned short* apd1   = (unsigned short*)(ws + 226746368);
    unsigned short* apd2   = (unsigned short*)(ws + 226783232);
    unsigned short* apd3   = (unsigned short*)(ws + 226848768);
    unsigned short* embbf  = (unsigned short*)(ws + 226850816);
    float*          hninit = (float*)(ws + 226916352);

    k_e1i<<<11454, 256, 0, stream>>>(x, e1w, e1b, h1p2, (unsigned int*)d_ws,
                                     e2w, e3w, d1w, d2w, d3w, emb,
                                     ape2, ape3, apd1, apd2, apd3, embbf, hninit);
    k_conv<32, 64, 16, 2, 0, 0><<<1024, 256, 0, stream>>>(h1p2, ape2, e2b, h2p);
    k_e3vq<<<1024, 256, 0, stream>>>(h2p, ape3, e3b, embbf, hninit, ze, zq, zqp);
    k_conv<64, 32, 18, 2, 66, 2><<<1024, 256, 0, stream>>>(zqp, apd1, d1b, d1op);
    k_d2f<<<4096, 256, 0, stream>>>(d1op, apd2, d2b, apd3, sc16);
    k_d3e<<<16384, 256, 0, stream>>>(sc16, d3b, xhat);
}